// Round 9
// baseline (583.614 us; speedup 1.0000x reference)
//
#include <hip/hip_runtime.h>

// Problem constants (from reference)
#define NVN 65536
#define NCN 32768
#define NB 4
#define DIM 32
#define NE 262144
#define HID 40
#define MSGD 20

#define WE2_STRIDE 36  // padded row stride for we2s (breaks h-row bank aliasing)

typedef unsigned short u16;
typedef unsigned int u32;

// bf16 helpers (RNE pack, cheap unpack)
__device__ __forceinline__ u16 f2bf(float f) {
    u32 u = __float_as_uint(f);
    u += 0x7fff + ((u >> 16) & 1);
    return (u16)(u >> 16);
}
__device__ __forceinline__ float bflo(u32 u) { return __uint_as_float(u << 16); }
__device__ __forceinline__ float bfhi(u32 u) { return __uint_as_float(u & 0xffff0000u); }

__device__ __forceinline__ void fma4(float4& acc, float a, const float4 w) {
    acc.x += a * w.x; acc.y += a * w.y; acc.z += a * w.z; acc.w += a * w.w;
}

// ---------------- CSR build (both sides fused) ----------------

__global__ __launch_bounds__(256) void hist_both(const int* __restrict__ to_x,
                                                 const int* __restrict__ to_z,
                                                 int* __restrict__ cnt_x,
                                                 int* __restrict__ cnt_z) {
    int bid = blockIdx.x;
    int e = (bid & 1023) * 256 + threadIdx.x;
    if (bid < 1024) atomicAdd(&cnt_x[to_x[e]], 1);
    else            atomicAdd(&cnt_z[to_z[e]], 1);
}

__global__ __launch_bounds__(1024) void scan_both(int* __restrict__ cnt_x,
                                                  int* __restrict__ cnt_z,
                                                  int* __restrict__ start_x,
                                                  int* __restrict__ start_z) {
    int side = blockIdx.x;
    int* counts = side ? cnt_z : cnt_x;   // re-written in place as scatter cursor
    int* start  = side ? start_z : start_x;
    __shared__ int sd[1024];
    int t = threadIdx.x;
    int base = t * 32;
    int local[32];
    int s = 0;
#pragma unroll
    for (int i = 0; i < 32; i++) { local[i] = counts[base + i]; s += local[i]; }
    sd[t] = s;
    __syncthreads();
    for (int off = 1; off < 1024; off <<= 1) {
        int v = (t >= off) ? sd[t - off] : 0;
        __syncthreads();
        sd[t] += v;
        __syncthreads();
    }
    int run = sd[t] - s;
#pragma unroll
    for (int i = 0; i < 32; i++) {
        start[base + i] = run;
        counts[base + i] = run;   // cursor init
        run += local[i];
    }
    if (t == 1023) start[NCN] = run;
}

__global__ __launch_bounds__(256) void scatter_both(const int* __restrict__ to_x,
                                                    const int* __restrict__ from_x,
                                                    const int* __restrict__ to_z,
                                                    const int* __restrict__ from_z,
                                                    int* __restrict__ cnt_x,
                                                    int* __restrict__ cnt_z,
                                                    u16* __restrict__ ef_x,
                                                    u16* __restrict__ ef_z) {
    int bid = blockIdx.x;
    int e = (bid & 1023) * 256 + threadIdx.x;
    const int* t; const int* f; int* cur; u16* ef;
    if (bid < 1024) { t = to_x; f = from_x; cur = cnt_x; ef = ef_x; }
    else            { t = to_z; f = from_z; cur = cnt_z; ef = ef_z; }
    int c = t[e];
    int pos = atomicAdd(&cur[c], 1);
    ef[pos] = (u16)f[e];
}

// ------- Precompute U2h[v][8][20] bf16, BOTH sides, 20 outputs/thread -------
// thread = (side, v, b, half). 160 LDS b128 reads/thread; VGPR ~60 -> high occupancy.

__global__ __launch_bounds__(256) void precompU_both(const float* __restrict__ h_from,
                                                     const float* __restrict__ Wm1_x,
                                                     const float* __restrict__ Wm1_z,
                                                     u16* __restrict__ U2h_x,
                                                     u16* __restrict__ U2h_z) {
    int side = blockIdx.x >> 11;
    const float* Wm1 = side ? Wm1_z : Wm1_x;
    u16* U2h = side ? U2h_z : U2h_x;

    __shared__ __attribute__((aligned(16))) float w[DIM * HID];
    int tid = threadIdx.x;
    for (int i = tid; i < DIM * HID; i += 256) w[i] = Wm1[i];
    __syncthreads();

    int gt = (blockIdx.x & 2047) * 256 + tid;
    int v = gt >> 3;
    int l8 = gt & 7;
    int b = l8 & 3;
    int hoff = (l8 >> 2) * 20;

    const float4* hf4 = (const float4*)(h_from + ((size_t)b * NVN + v) * DIM);
    float4 acc4[5];
#pragma unroll
    for (int jq = 0; jq < 5; jq++) acc4[jq] = make_float4(0.f, 0.f, 0.f, 0.f);
#pragma unroll
    for (int q = 0; q < DIM / 4; q++) {
        float4 x = hf4[q];
#define WROW(xr, row) { const float4* w4_ = (const float4*)(w + (row) * HID + hoff); \
        fma4(acc4[0], (xr), w4_[0]); fma4(acc4[1], (xr), w4_[1]); \
        fma4(acc4[2], (xr), w4_[2]); fma4(acc4[3], (xr), w4_[3]); \
        fma4(acc4[4], (xr), w4_[4]); }
        WROW(x.x, 4 * q + 0) WROW(x.y, 4 * q + 1) WROW(x.z, 4 * q + 2) WROW(x.w, 4 * q + 3)
#undef WROW
    }
    uint2* d2 = (uint2*)(U2h + (size_t)v * 160 + l8 * 20);
#pragma unroll
    for (int jq = 0; jq < 5; jq++) {
        u32 p0 = (u32)f2bf(acc4[jq].x) | ((u32)f2bf(acc4[jq].y) << 16);
        u32 p1 = (u32)f2bf(acc4[jq].z) | ((u32)f2bf(acc4[jq].w) << 16);
        d2[jq] = make_uint2(p0, p1);
    }
}

// ------- Fused T/P-compute + aggregate + embed MLP, BOTH SIDES, one dispatch -------
// 8 lanes per (c): lane = (b, half) owns 20 comps. T/P have ZERO reuse across agg
// threads, so they are computed in-thread (f32, from h_to) instead of staged via the
// stall-bound precompTP kernel (r7/r8: 143us at 13% VALUBusy).
// NOTE: no min-waves clamp — VGPR must float (~100) or the edge loop spills.

__global__ __launch_bounds__(256) void agg_kernel(
        const u16* __restrict__ U2h_x, const u16* __restrict__ U2h_z,
        const float* __restrict__ h_to_x, const float* __restrict__ h_to_z,
        const float* __restrict__ logit_x, const float* __restrict__ logit_z,
        const int* __restrict__ start_x, const int* __restrict__ start_z,
        const u16* __restrict__ ef_x, const u16* __restrict__ ef_z,
        const float* __restrict__ Wm1_x, const float* __restrict__ Wm1_z,
        const float* __restrict__ Wm2_x, const float* __restrict__ Wm2_z,
        const float* __restrict__ We1_x, const float* __restrict__ We1_z,
        const float* __restrict__ We2_x, const float* __restrict__ We2_z,
        float* __restrict__ out) {
    int side = blockIdx.x >> 10;
    const u16* U2h = side ? U2h_z : U2h_x;
    const float* h_to = side ? h_to_z : h_to_x;
    const float* logit = side ? logit_z : logit_x;
    const int* start = side ? start_z : start_x;
    const u16* ef = side ? ef_z : ef_x;
    const float* Wm1 = side ? Wm1_z : Wm1_x;
    const float* Wm2 = side ? Wm2_z : Wm2_x;
    const float* We1 = side ? We1_z : We1_x;
    const float* We2 = side ? We2_z : We2_x;

    __shared__ __attribute__((aligned(16))) float wm1bs[DIM * HID];        // Wm1 rows 32..63
    __shared__ __attribute__((aligned(16))) float we1bs[DIM * HID];        // We1 rows 20..51
    __shared__ __attribute__((aligned(16))) float we1ls[HID + 8];          // We1 row 52 (+pad)
    __shared__ __attribute__((aligned(16))) float wm2s[HID * MSGD];        // [40][20]
    __shared__ __attribute__((aligned(16))) float we1as[MSGD * HID];       // We1 rows 0..19
    __shared__ __attribute__((aligned(16))) float we2s[HID * WE2_STRIDE];  // [40][36]
    int tid = threadIdx.x;
    for (int i = tid; i < DIM * HID; i += 256) {
        wm1bs[i] = Wm1[DIM * HID + i];          // rows 32..63 of Wm1
        we1bs[i] = We1[MSGD * HID + i];         // rows 20..51 of We1
    }
    for (int i = tid; i < HID * MSGD; i += 256) { wm2s[i] = Wm2[i]; we1as[i] = We1[i]; }
    for (int i = tid; i < HID * DIM; i += 256) {
        int h = i >> 5, d = i & 31;
        we2s[h * WE2_STRIDE + d] = We2[i];
    }
    if (tid < HID) we1ls[tid] = We1[(MSGD + DIM) * HID + tid];  // row 52
    __syncthreads();

    int gt = (blockIdx.x & 1023) * 256 + tid;
    int c = gt >> 3;
    int l8 = gt & 7;
    int b = l8 & 3;
    int half = l8 >> 2;
    int hoff = half * 20;

    // start/ef early: begin the dependent gather chain before the matvec
    int e0 = start[c], e1 = start[c + 1];
    int cnt = e1 - e0;
    int vA = (cnt > 0) ? (int)ef[e0] : 0;
    int vB = (cnt > 1) ? (int)ef[e0 + 1] : 0;

    // ---- in-thread T/P: t = X @ Wm1[32:64][:,hoff:], p = X @ We1[20:52][:,hoff:] + lg*we1l ----
    float4 t4[5], p4[5];
    {
        float lg = logit[(size_t)b * NCN + c];
        const float4* wl = (const float4*)(we1ls + hoff);
#pragma unroll
        for (int jq = 0; jq < 5; jq++) {
            float4 wv = wl[jq];
            p4[jq] = make_float4(lg * wv.x, lg * wv.y, lg * wv.z, lg * wv.w);
            t4[jq] = make_float4(0.f, 0.f, 0.f, 0.f);
        }
        const float4* Xp = (const float4*)(h_to + ((size_t)b * NCN + c) * DIM);
#define TPROW(xr, row) { \
        const float4* wa_ = (const float4*)(wm1bs + (row) * HID + hoff); \
        const float4* wb_ = (const float4*)(we1bs + (row) * HID + hoff); \
        fma4(t4[0], (xr), wa_[0]); fma4(t4[1], (xr), wa_[1]); fma4(t4[2], (xr), wa_[2]); \
        fma4(t4[3], (xr), wa_[3]); fma4(t4[4], (xr), wa_[4]); \
        fma4(p4[0], (xr), wb_[0]); fma4(p4[1], (xr), wb_[1]); fma4(p4[2], (xr), wb_[2]); \
        fma4(p4[3], (xr), wb_[3]); fma4(p4[4], (xr), wb_[4]); }
#pragma unroll
        for (int q = 0; q < DIM / 4; q++) {
            float4 x = Xp[q];
            TPROW(x.x, 4 * q + 0) TPROW(x.y, 4 * q + 1)
            TPROW(x.z, 4 * q + 2) TPROW(x.w, 4 * q + 3)
        }
#undef TPROW
    }

    // ---- edge loop: s = sum relu(u + t), 2-edge-deep pipeline ----
    float s[20];
#pragma unroll
    for (int k = 0; k < 20; k++) s[k] = 0.f;

    const u16* Ub = U2h + l8 * 20;
    int i = e0;

#define CONS2(W, tq, base) { \
    s[(base) + 0] += fmaxf(bflo(W.x) + tq.x, 0.f); \
    s[(base) + 1] += fmaxf(bfhi(W.x) + tq.y, 0.f); \
    s[(base) + 2] += fmaxf(bflo(W.y) + tq.z, 0.f); \
    s[(base) + 3] += fmaxf(bfhi(W.y) + tq.w, 0.f); }

    while (cnt >= 2) {
        const uint2* pa = (const uint2*)(Ub + (size_t)vA * 160);
        const uint2* pb = (const uint2*)(Ub + (size_t)vB * 160);
        uint2 A0 = pa[0], A1 = pa[1], A2 = pa[2], A3 = pa[3], A4 = pa[4];
        uint2 B0 = pb[0], B1 = pb[1], B2 = pb[2], B3 = pb[3], B4 = pb[4];
        int vA2 = (cnt > 2) ? (int)ef[i + 2] : 0;
        int vB2 = (cnt > 3) ? (int)ef[i + 3] : 0;
        CONS2(A0, t4[0], 0) CONS2(A1, t4[1], 4) CONS2(A2, t4[2], 8)
        CONS2(A3, t4[3], 12) CONS2(A4, t4[4], 16)
        CONS2(B0, t4[0], 0) CONS2(B1, t4[1], 4) CONS2(B2, t4[2], 8)
        CONS2(B3, t4[3], 12) CONS2(B4, t4[4], 16)
        vA = vA2; vB = vB2; i += 2; cnt -= 2;
    }
    if (cnt == 1) {
        const uint2* pa = (const uint2*)(Ub + (size_t)vA * 160);
        uint2 A0 = pa[0], A1 = pa[1], A2 = pa[2], A3 = pa[3], A4 = pa[4];
        CONS2(A0, t4[0], 0) CONS2(A1, t4[1], 4) CONS2(A2, t4[2], 8)
        CONS2(A3, t4[3], 12) CONS2(A4, t4[4], 16)
    }
#undef CONS2

    // ---- m partial: this lane's 20 h-rows of Wm2 ----
    float4 m4[5];
#pragma unroll
    for (int kq = 0; kq < 5; kq++) m4[kq] = make_float4(0.f, 0.f, 0.f, 0.f);
    const float* wmbase = wm2s + hoff * MSGD;
#define MROW(sv, k) { const float4* w4_ = (const float4*)(wmbase + (k) * MSGD); \
    fma4(m4[0], (sv), w4_[0]); fma4(m4[1], (sv), w4_[1]); fma4(m4[2], (sv), w4_[2]); \
    fma4(m4[3], (sv), w4_[3]); fma4(m4[4], (sv), w4_[4]); }
    MROW(s[0], 0)   MROW(s[1], 1)   MROW(s[2], 2)   MROW(s[3], 3)
    MROW(s[4], 4)   MROW(s[5], 5)   MROW(s[6], 6)   MROW(s[7], 7)
    MROW(s[8], 8)   MROW(s[9], 9)   MROW(s[10], 10) MROW(s[11], 11)
    MROW(s[12], 12) MROW(s[13], 13) MROW(s[14], 14) MROW(s[15], 15)
    MROW(s[16], 16) MROW(s[17], 17) MROW(s[18], 18) MROW(s[19], 19)
#undef MROW

    float mm[MSGD];
#pragma unroll
    for (int kq = 0; kq < 5; kq++) {
        mm[4 * kq + 0] = m4[kq].x; mm[4 * kq + 1] = m4[kq].y;
        mm[4 * kq + 2] = m4[kq].z; mm[4 * kq + 3] = m4[kq].w;
    }
    // combine the two comp-halves (lane ^ 4) -> full m in every lane
#pragma unroll
    for (int k = 0; k < MSGD; k++) mm[k] += __shfl_xor(mm[k], 4);

    // ---- a = relu(m @ We1[0:20] + p) for this lane's 20 components ----
    float4 a0 = p4[0], a1 = p4[1], a2 = p4[2], a3 = p4[3], a4 = p4[4];
#pragma unroll
    for (int k = 0; k < MSGD; k++) {
        float mk = mm[k];
        const float4* w4 = (const float4*)(we1as + k * HID + hoff);
        fma4(a0, mk, w4[0]); fma4(a1, mk, w4[1]); fma4(a2, mk, w4[2]);
        fma4(a3, mk, w4[3]); fma4(a4, mk, w4[4]);
    }
    a0.x = fmaxf(a0.x, 0.f); a0.y = fmaxf(a0.y, 0.f); a0.z = fmaxf(a0.z, 0.f); a0.w = fmaxf(a0.w, 0.f);
    a1.x = fmaxf(a1.x, 0.f); a1.y = fmaxf(a1.y, 0.f); a1.z = fmaxf(a1.z, 0.f); a1.w = fmaxf(a1.w, 0.f);
    a2.x = fmaxf(a2.x, 0.f); a2.y = fmaxf(a2.y, 0.f); a2.z = fmaxf(a2.z, 0.f); a2.w = fmaxf(a2.w, 0.f);
    a3.x = fmaxf(a3.x, 0.f); a3.y = fmaxf(a3.y, 0.f); a3.z = fmaxf(a3.z, 0.f); a3.w = fmaxf(a3.w, 0.f);
    a4.x = fmaxf(a4.x, 0.f); a4.y = fmaxf(a4.y, 0.f); a4.z = fmaxf(a4.z, 0.f); a4.w = fmaxf(a4.w, 0.f);

    // ---- o partial: this lane's 20 h-rows of We2 ----
    float4 o4[8];
#pragma unroll
    for (int dq = 0; dq < 8; dq++) o4[dq] = make_float4(0.f, 0.f, 0.f, 0.f);
    const float* wobase = we2s + hoff * WE2_STRIDE;
#define OROW(av, k) { const float4* w4_ = (const float4*)(wobase + (k) * WE2_STRIDE); \
    fma4(o4[0], (av), w4_[0]); fma4(o4[1], (av), w4_[1]); fma4(o4[2], (av), w4_[2]); \
    fma4(o4[3], (av), w4_[3]); fma4(o4[4], (av), w4_[4]); fma4(o4[5], (av), w4_[5]); \
    fma4(o4[6], (av), w4_[6]); fma4(o4[7], (av), w4_[7]); }
    OROW(a0.x, 0)  OROW(a0.y, 1)  OROW(a0.z, 2)  OROW(a0.w, 3)
    OROW(a1.x, 4)  OROW(a1.y, 5)  OROW(a1.z, 6)  OROW(a1.w, 7)
    OROW(a2.x, 8)  OROW(a2.y, 9)  OROW(a2.z, 10) OROW(a2.w, 11)
    OROW(a3.x, 12) OROW(a3.y, 13) OROW(a3.z, 14) OROW(a3.w, 15)
    OROW(a4.x, 16) OROW(a4.y, 17) OROW(a4.z, 18) OROW(a4.w, 19)
#undef OROW

    float oo[DIM];
#pragma unroll
    for (int dq = 0; dq < 8; dq++) {
        oo[4 * dq + 0] = o4[dq].x; oo[4 * dq + 1] = o4[dq].y;
        oo[4 * dq + 2] = o4[dq].z; oo[4 * dq + 3] = o4[dq].w;
    }
#pragma unroll
    for (int d = 0; d < DIM; d++) oo[d] += __shfl_xor(oo[d], 4);

    float4* Orow = (float4*)(out + (size_t)side * (NB * NCN * DIM)
                                 + ((size_t)b * NCN + c) * DIM);
    if (half == 0) {
        Orow[0] = make_float4(oo[0], oo[1], oo[2], oo[3]);
        Orow[1] = make_float4(oo[4], oo[5], oo[6], oo[7]);
        Orow[2] = make_float4(oo[8], oo[9], oo[10], oo[11]);
        Orow[3] = make_float4(oo[12], oo[13], oo[14], oo[15]);
    } else {
        Orow[4] = make_float4(oo[16], oo[17], oo[18], oo[19]);
        Orow[5] = make_float4(oo[20], oo[21], oo[22], oo[23]);
        Orow[6] = make_float4(oo[24], oo[25], oo[26], oo[27]);
        Orow[7] = make_float4(oo[28], oo[29], oo[30], oo[31]);
    }
}

// ---------------- host ----------------

extern "C" void kernel_launch(void* const* d_in, const int* in_sizes, int n_in,
                              void* d_out, int out_size, void* d_ws, size_t ws_size,
                              hipStream_t stream) {
    const float* h_from   = (const float*)d_in[0];
    const float* h_to_x   = (const float*)d_in[1];
    const float* h_to_z   = (const float*)d_in[2];
    const float* hx_logit = (const float*)d_in[3];
    const float* hz_logit = (const float*)d_in[4];
    const int*   from_x   = (const int*)d_in[5];
    const int*   to_x     = (const int*)d_in[6];
    const int*   from_z   = (const int*)d_in[7];
    const int*   to_z     = (const int*)d_in[8];
    const float* Wm1_x    = (const float*)d_in[9];
    const float* Wm2_x    = (const float*)d_in[10];
    const float* Wm1_z    = (const float*)d_in[11];
    const float* Wm2_z    = (const float*)d_in[12];
    const float* We1_x    = (const float*)d_in[13];
    const float* We2_x    = (const float*)d_in[14];
    const float* We1_z    = (const float*)d_in[15];
    const float* We2_z    = (const float*)d_in[16];

    // Workspace layout (bytes), end = 43,253,768 (well within proven budget)
    char* ws = (char*)d_ws;
    u16* U2h_x = (u16*)(ws);                       // 65536*8*20*2 = 20,971,520
    u16* U2h_z = (u16*)(ws + 20971520);            // 20,971,520
    u16* ef_x  = (u16*)(ws + 41943040);            // 524,288
    u16* ef_z  = (u16*)(ws + 42467328);            // 524,288
    int* start_x = (int*)(ws + 42991616);          // 131,076
    int* start_z = (int*)(ws + 43122696);          // 131,076
    // counts/cursors alias U2h_x head: dead before precompU writes it (stream order)
    int* cnt_x = (int*)(ws + 0);
    int* cnt_z = (int*)(ws + 131072);
    float* out = (float*)d_out;

    hipMemsetAsync(ws, 0, 262144, stream);  // zero cnt_x + cnt_z
    hist_both<<<2048, 256, 0, stream>>>(to_x, to_z, cnt_x, cnt_z);
    scan_both<<<2, 1024, 0, stream>>>(cnt_x, cnt_z, start_x, start_z);
    scatter_both<<<2048, 256, 0, stream>>>(to_x, from_x, to_z, from_z,
                                           cnt_x, cnt_z, ef_x, ef_z);

    precompU_both<<<4096, 256, 0, stream>>>(h_from, Wm1_x, Wm1_z, U2h_x, U2h_z);

    agg_kernel<<<2048, 256, 0, stream>>>(U2h_x, U2h_z, h_to_x, h_to_z,
                                         hx_logit, hz_logit,
                                         start_x, start_z, ef_x, ef_z,
                                         Wm1_x, Wm1_z, Wm2_x, Wm2_z,
                                         We1_x, We1_z, We2_x, We2_z, out);
}

// Round 10
// 246.375 us; speedup vs baseline: 2.3688x; 2.3688x over previous
//
#include <hip/hip_runtime.h>

// Problem constants (from reference)
#define NVN 65536
#define NCN 32768
#define NB 4
#define DIM 32
#define NE 262144
#define HID 40
#define MSGD 20

#define WE2_STRIDE 36  // padded row stride for we2s (breaks h-row bank aliasing)

typedef unsigned short u16;
typedef unsigned int u32;

// bf16 helpers (RNE pack, cheap unpack)
__device__ __forceinline__ u16 f2bf(float f) {
    u32 u = __float_as_uint(f);
    u += 0x7fff + ((u >> 16) & 1);
    return (u16)(u >> 16);
}
__device__ __forceinline__ float bflo(u32 u) { return __uint_as_float(u << 16); }
__device__ __forceinline__ float bfhi(u32 u) { return __uint_as_float(u & 0xffff0000u); }

__device__ __forceinline__ void fma4(float4& acc, float a, const float4 w) {
    acc.x += a * w.x; acc.y += a * w.y; acc.z += a * w.z; acc.w += a * w.w;
}

// ---------------- CSR build (both sides fused) ----------------

__global__ __launch_bounds__(256) void hist_both(const int* __restrict__ to_x,
                                                 const int* __restrict__ to_z,
                                                 int* __restrict__ cnt_x,
                                                 int* __restrict__ cnt_z) {
    int bid = blockIdx.x;
    int e = (bid & 1023) * 256 + threadIdx.x;
    if (bid < 1024) atomicAdd(&cnt_x[to_x[e]], 1);
    else            atomicAdd(&cnt_z[to_z[e]], 1);
}

__global__ __launch_bounds__(1024) void scan_both(int* __restrict__ cnt_x,
                                                  int* __restrict__ cnt_z,
                                                  int* __restrict__ start_x,
                                                  int* __restrict__ start_z) {
    int side = blockIdx.x;
    int* counts = side ? cnt_z : cnt_x;   // re-written in place as scatter cursor
    int* start  = side ? start_z : start_x;
    __shared__ int sd[1024];
    int t = threadIdx.x;
    int base = t * 32;
    int local[32];
    int s = 0;
#pragma unroll
    for (int i = 0; i < 32; i++) { local[i] = counts[base + i]; s += local[i]; }
    sd[t] = s;
    __syncthreads();
    for (int off = 1; off < 1024; off <<= 1) {
        int v = (t >= off) ? sd[t - off] : 0;
        __syncthreads();
        sd[t] += v;
        __syncthreads();
    }
    int run = sd[t] - s;
#pragma unroll
    for (int i = 0; i < 32; i++) {
        start[base + i] = run;
        counts[base + i] = run;   // cursor init
        run += local[i];
    }
    if (t == 1023) start[NCN] = run;
}

__global__ __launch_bounds__(256) void scatter_both(const int* __restrict__ to_x,
                                                    const int* __restrict__ from_x,
                                                    const int* __restrict__ to_z,
                                                    const int* __restrict__ from_z,
                                                    int* __restrict__ cnt_x,
                                                    int* __restrict__ cnt_z,
                                                    u16* __restrict__ ef_x,
                                                    u16* __restrict__ ef_z) {
    int bid = blockIdx.x;
    int e = (bid & 1023) * 256 + threadIdx.x;
    const int* t; const int* f; int* cur; u16* ef;
    if (bid < 1024) { t = to_x; f = from_x; cur = cnt_x; ef = ef_x; }
    else            { t = to_z; f = from_z; cur = cnt_z; ef = ef_z; }
    int c = t[e];
    int pos = atomicAdd(&cur[c], 1);
    ef[pos] = (u16)f[e];
}

// ------- Precompute U2h[v][8][20] bf16, BOTH sides, 20 outputs/thread -------
// thread = (side, v, b, half). acc4[5] keeps VGPR ~60 -> high occupancy (r9: worked).

__global__ __launch_bounds__(256) void precompU_both(const float* __restrict__ h_from,
                                                     const float* __restrict__ Wm1_x,
                                                     const float* __restrict__ Wm1_z,
                                                     u16* __restrict__ U2h_x,
                                                     u16* __restrict__ U2h_z) {
    int side = blockIdx.x >> 11;
    const float* Wm1 = side ? Wm1_z : Wm1_x;
    u16* U2h = side ? U2h_z : U2h_x;

    __shared__ __attribute__((aligned(16))) float w[DIM * HID];
    int tid = threadIdx.x;
    for (int i = tid; i < DIM * HID; i += 256) w[i] = Wm1[i];
    __syncthreads();

    int gt = (blockIdx.x & 2047) * 256 + tid;
    int v = gt >> 3;
    int l8 = gt & 7;
    int b = l8 & 3;
    int hoff = (l8 >> 2) * 20;

    const float4* hf4 = (const float4*)(h_from + ((size_t)b * NVN + v) * DIM);
    float4 acc4[5];
#pragma unroll
    for (int jq = 0; jq < 5; jq++) acc4[jq] = make_float4(0.f, 0.f, 0.f, 0.f);
#pragma unroll
    for (int q = 0; q < DIM / 4; q++) {
        float4 x = hf4[q];
#define WROW(xr, row) { const float4* w4_ = (const float4*)(w + (row) * HID + hoff); \
        fma4(acc4[0], (xr), w4_[0]); fma4(acc4[1], (xr), w4_[1]); \
        fma4(acc4[2], (xr), w4_[2]); fma4(acc4[3], (xr), w4_[3]); \
        fma4(acc4[4], (xr), w4_[4]); }
        WROW(x.x, 4 * q + 0) WROW(x.y, 4 * q + 1) WROW(x.z, 4 * q + 2) WROW(x.w, 4 * q + 3)
#undef WROW
    }
    uint2* d2 = (uint2*)(U2h + (size_t)v * 160 + l8 * 20);
#pragma unroll
    for (int jq = 0; jq < 5; jq++) {
        u32 p0 = (u32)f2bf(acc4[jq].x) | ((u32)f2bf(acc4[jq].y) << 16);
        u32 p1 = (u32)f2bf(acc4[jq].z) | ((u32)f2bf(acc4[jq].w) << 16);
        d2[jq] = make_uint2(p0, p1);
    }
}

// ------- Precompute T2h[c][8][20], P2h[c][8][20] bf16, BOTH sides, 20 out/thread -------
// thread = (side, c, b, half, which). r8's 40-out/thread version held 40 f32 accs
// through a 320-deep LDS chain at VGPR=136 / 11% occupancy -> 143us latency-bound.
// Splitting which=T/P across threads halves live state AND chain depth, doubles waves.

__global__ __launch_bounds__(256) void precompTP_both(
        const float* __restrict__ h_to_x, const float* __restrict__ h_to_z,
        const float* __restrict__ logit_x, const float* __restrict__ logit_z,
        const float* __restrict__ Wm1_x, const float* __restrict__ Wm1_z,
        const float* __restrict__ We1_x, const float* __restrict__ We1_z,
        u16* __restrict__ T2h_x, u16* __restrict__ T2h_z,
        u16* __restrict__ P2h_x, u16* __restrict__ P2h_z) {
    int side = blockIdx.x >> 11;
    const float* h_to = side ? h_to_z : h_to_x;
    const float* logit = side ? logit_z : logit_x;
    const float* Wm1 = side ? Wm1_z : Wm1_x;
    const float* We1 = side ? We1_z : We1_x;
    u16* T2h = side ? T2h_z : T2h_x;
    u16* P2h = side ? P2h_z : P2h_x;

    __shared__ __attribute__((aligned(16))) float wm1b[DIM * HID];
    __shared__ __attribute__((aligned(16))) float we1b[DIM * HID];
    __shared__ float we1l[HID];
    int tid = threadIdx.x;
    for (int i = tid; i < DIM * HID; i += 256) {
        wm1b[i] = Wm1[DIM * HID + i];   // rows 32..63 of Wm1
        we1b[i] = We1[MSGD * HID + i];  // rows 20..51 of We1
    }
    if (tid < HID) we1l[tid] = We1[(MSGD + DIM) * HID + tid];  // row 52
    __syncthreads();

    int gt = (blockIdx.x & 2047) * 256 + tid;
    int c = gt >> 4;
    int l16 = gt & 15;
    int b = l16 & 3;
    int half = (l16 >> 2) & 1;
    int which = l16 >> 3;          // 0: T, 1: P
    int hoff = half * 20;

    const float4* h4 = (const float4*)(h_to + ((size_t)b * NCN + c) * DIM);
    float lg = logit[(size_t)b * NCN + c];
    float lginit = which ? lg : 0.f;
    const float* wsel = which ? we1b : wm1b;

    float4 acc4[5];
    {
        const float4* wl = (const float4*)(we1l + hoff);
#pragma unroll
        for (int jq = 0; jq < 5; jq++) {
            float4 wv = wl[jq];
            acc4[jq] = make_float4(lginit * wv.x, lginit * wv.y, lginit * wv.z, lginit * wv.w);
        }
    }
#pragma unroll
    for (int q = 0; q < DIM / 4; q++) {
        float4 x = h4[q];
#define WROW(xr, row) { const float4* w4_ = (const float4*)(wsel + (row) * HID + hoff); \
        fma4(acc4[0], (xr), w4_[0]); fma4(acc4[1], (xr), w4_[1]); \
        fma4(acc4[2], (xr), w4_[2]); fma4(acc4[3], (xr), w4_[3]); \
        fma4(acc4[4], (xr), w4_[4]); }
        WROW(x.x, 4 * q + 0) WROW(x.y, 4 * q + 1) WROW(x.z, 4 * q + 2) WROW(x.w, 4 * q + 3)
#undef WROW
    }
    uint2* d2 = (uint2*)((which ? P2h : T2h) + (size_t)c * 160 + (half * 4 + b) * 20);
#pragma unroll
    for (int jq = 0; jq < 5; jq++) {
        u32 p0 = (u32)f2bf(acc4[jq].x) | ((u32)f2bf(acc4[jq].y) << 16);
        u32 p1 = (u32)f2bf(acc4[jq].z) | ((u32)f2bf(acc4[jq].w) << 16);
        d2[jq] = make_uint2(p0, p1);
    }
}

// ------- Fused aggregate + embed MLP, BOTH SIDES in one dispatch (r8, proven) -------
// 8 lanes per (c): lane = (b, half) owns 20 comps; group gathers one contiguous
// 320B bf16 U2h line per edge; 2-edge-deep manual pipeline (banks A/B).
// NOTE: no min-waves clamp — VGPR must float (~76) or the edge loop spills
// (r9 fusion attempt: VGPR 256, 577MB scratch writes, 571us — reverted).

__global__ __launch_bounds__(256) void agg_kernel(
        const u16* __restrict__ U2h_x, const u16* __restrict__ U2h_z,
        const u16* __restrict__ T2h_x, const u16* __restrict__ T2h_z,
        const u16* __restrict__ P2h_x, const u16* __restrict__ P2h_z,
        const int* __restrict__ start_x, const int* __restrict__ start_z,
        const u16* __restrict__ ef_x, const u16* __restrict__ ef_z,
        const float* __restrict__ Wm2_x, const float* __restrict__ Wm2_z,
        const float* __restrict__ We1_x, const float* __restrict__ We1_z,
        const float* __restrict__ We2_x, const float* __restrict__ We2_z,
        float* __restrict__ out) {
    int side = blockIdx.x >> 10;
    const u16* U2h = side ? U2h_z : U2h_x;
    const u16* T2h = side ? T2h_z : T2h_x;
    const u16* P2h = side ? P2h_z : P2h_x;
    const int* start = side ? start_z : start_x;
    const u16* ef = side ? ef_z : ef_x;
    const float* Wm2 = side ? Wm2_z : Wm2_x;
    const float* We1 = side ? We1_z : We1_x;
    const float* We2 = side ? We2_z : We2_x;

    __shared__ __attribute__((aligned(16))) float wm2s[HID * MSGD];        // [40][20]
    __shared__ __attribute__((aligned(16))) float we1s[MSGD * HID];        // [20][40]
    __shared__ __attribute__((aligned(16))) float we2s[HID * WE2_STRIDE];  // [40][36]
    int tid = threadIdx.x;
    for (int i = tid; i < HID * MSGD; i += 256) { wm2s[i] = Wm2[i]; we1s[i] = We1[i]; }
    for (int i = tid; i < HID * DIM; i += 256) {
        int h = i >> 5, d = i & 31;
        we2s[h * WE2_STRIDE + d] = We2[i];
    }
    __syncthreads();

    int gt = (blockIdx.x & 1023) * 256 + tid;
    int c = gt >> 3;
    int l8 = gt & 7;
    int b = l8 & 3;
    int half = l8 >> 2;
    int hoff = half * 20;

    // T slice: 20 bf16 -> 20 f32 regs
    float t[20];
    {
        const uint2* tp = (const uint2*)(T2h + (size_t)c * 160 + l8 * 20);
#pragma unroll
        for (int q = 0; q < 5; q++) {
            uint2 wv = tp[q];
            t[4 * q + 0] = bflo(wv.x); t[4 * q + 1] = bfhi(wv.x);
            t[4 * q + 2] = bflo(wv.y); t[4 * q + 3] = bfhi(wv.y);
        }
    }

    float s[20];
#pragma unroll
    for (int k = 0; k < 20; k++) s[k] = 0.f;

    int e0 = start[c], e1 = start[c + 1];
    const u16* Ub = U2h + l8 * 20;
    int i = e0;
    int cnt = e1 - e0;
    int vA = (cnt > 0) ? (int)ef[i] : 0;
    int vB = (cnt > 1) ? (int)ef[i + 1] : 0;

#define CONS2(W, base) { \
    s[(base) + 0] += fmaxf(bflo(W.x) + t[(base) + 0], 0.f); \
    s[(base) + 1] += fmaxf(bfhi(W.x) + t[(base) + 1], 0.f); \
    s[(base) + 2] += fmaxf(bflo(W.y) + t[(base) + 2], 0.f); \
    s[(base) + 3] += fmaxf(bfhi(W.y) + t[(base) + 3], 0.f); }

    while (cnt >= 2) {
        const uint2* pa = (const uint2*)(Ub + (size_t)vA * 160);
        const uint2* pb = (const uint2*)(Ub + (size_t)vB * 160);
        uint2 A0 = pa[0], A1 = pa[1], A2 = pa[2], A3 = pa[3], A4 = pa[4];
        uint2 B0 = pb[0], B1 = pb[1], B2 = pb[2], B3 = pb[3], B4 = pb[4];
        int vA2 = (cnt > 2) ? (int)ef[i + 2] : 0;
        int vB2 = (cnt > 3) ? (int)ef[i + 3] : 0;
        CONS2(A0, 0) CONS2(A1, 4) CONS2(A2, 8) CONS2(A3, 12) CONS2(A4, 16)
        CONS2(B0, 0) CONS2(B1, 4) CONS2(B2, 8) CONS2(B3, 12) CONS2(B4, 16)
        vA = vA2; vB = vB2; i += 2; cnt -= 2;
    }
    if (cnt == 1) {
        const uint2* pa = (const uint2*)(Ub + (size_t)vA * 160);
        uint2 A0 = pa[0], A1 = pa[1], A2 = pa[2], A3 = pa[3], A4 = pa[4];
        CONS2(A0, 0) CONS2(A1, 4) CONS2(A2, 8) CONS2(A3, 12) CONS2(A4, 16)
    }
#undef CONS2

    // ---- m partial: this lane's 20 h-rows of Wm2 ----
    float4 m4[5];
#pragma unroll
    for (int kq = 0; kq < 5; kq++) m4[kq] = make_float4(0.f, 0.f, 0.f, 0.f);
    const float* wmbase = wm2s + hoff * MSGD;
#define MROW(sv, k) { const float4* w4_ = (const float4*)(wmbase + (k) * MSGD); \
    fma4(m4[0], (sv), w4_[0]); fma4(m4[1], (sv), w4_[1]); fma4(m4[2], (sv), w4_[2]); \
    fma4(m4[3], (sv), w4_[3]); fma4(m4[4], (sv), w4_[4]); }
    MROW(s[0], 0)   MROW(s[1], 1)   MROW(s[2], 2)   MROW(s[3], 3)
    MROW(s[4], 4)   MROW(s[5], 5)   MROW(s[6], 6)   MROW(s[7], 7)
    MROW(s[8], 8)   MROW(s[9], 9)   MROW(s[10], 10) MROW(s[11], 11)
    MROW(s[12], 12) MROW(s[13], 13) MROW(s[14], 14) MROW(s[15], 15)
    MROW(s[16], 16) MROW(s[17], 17) MROW(s[18], 18) MROW(s[19], 19)
#undef MROW

    float mm[MSGD];
#pragma unroll
    for (int kq = 0; kq < 5; kq++) {
        mm[4 * kq + 0] = m4[kq].x; mm[4 * kq + 1] = m4[kq].y;
        mm[4 * kq + 2] = m4[kq].z; mm[4 * kq + 3] = m4[kq].w;
    }
    // combine the two comp-halves (lane ^ 4) -> full m in every lane
#pragma unroll
    for (int k = 0; k < MSGD; k++) mm[k] += __shfl_xor(mm[k], 4);

    // ---- a = relu(m @ We1[0:20] + P) for this lane's 20 components ----
    float4 a0, a1, a2, a3, a4;
    {
        const uint2* pp = (const uint2*)(P2h + (size_t)c * 160 + l8 * 20);
        uint2 w0 = pp[0], w1 = pp[1], w2 = pp[2], w3 = pp[3], w4v = pp[4];
        a0 = make_float4(bflo(w0.x), bfhi(w0.x), bflo(w0.y), bfhi(w0.y));
        a1 = make_float4(bflo(w1.x), bfhi(w1.x), bflo(w1.y), bfhi(w1.y));
        a2 = make_float4(bflo(w2.x), bfhi(w2.x), bflo(w2.y), bfhi(w2.y));
        a3 = make_float4(bflo(w3.x), bfhi(w3.x), bflo(w3.y), bfhi(w3.y));
        a4 = make_float4(bflo(w4v.x), bfhi(w4v.x), bflo(w4v.y), bfhi(w4v.y));
    }
#pragma unroll
    for (int k = 0; k < MSGD; k++) {
        float mk = mm[k];
        const float4* w4 = (const float4*)(we1s + k * HID + hoff);
        fma4(a0, mk, w4[0]); fma4(a1, mk, w4[1]); fma4(a2, mk, w4[2]);
        fma4(a3, mk, w4[3]); fma4(a4, mk, w4[4]);
    }
    a0.x = fmaxf(a0.x, 0.f); a0.y = fmaxf(a0.y, 0.f); a0.z = fmaxf(a0.z, 0.f); a0.w = fmaxf(a0.w, 0.f);
    a1.x = fmaxf(a1.x, 0.f); a1.y = fmaxf(a1.y, 0.f); a1.z = fmaxf(a1.z, 0.f); a1.w = fmaxf(a1.w, 0.f);
    a2.x = fmaxf(a2.x, 0.f); a2.y = fmaxf(a2.y, 0.f); a2.z = fmaxf(a2.z, 0.f); a2.w = fmaxf(a2.w, 0.f);
    a3.x = fmaxf(a3.x, 0.f); a3.y = fmaxf(a3.y, 0.f); a3.z = fmaxf(a3.z, 0.f); a3.w = fmaxf(a3.w, 0.f);
    a4.x = fmaxf(a4.x, 0.f); a4.y = fmaxf(a4.y, 0.f); a4.z = fmaxf(a4.z, 0.f); a4.w = fmaxf(a4.w, 0.f);

    // ---- o partial: this lane's 20 h-rows of We2 ----
    float4 o4[8];
#pragma unroll
    for (int dq = 0; dq < 8; dq++) o4[dq] = make_float4(0.f, 0.f, 0.f, 0.f);
    const float* wobase = we2s + hoff * WE2_STRIDE;
#define OROW(av, k) { const float4* w4_ = (const float4*)(wobase + (k) * WE2_STRIDE); \
    fma4(o4[0], (av), w4_[0]); fma4(o4[1], (av), w4_[1]); fma4(o4[2], (av), w4_[2]); \
    fma4(o4[3], (av), w4_[3]); fma4(o4[4], (av), w4_[4]); fma4(o4[5], (av), w4_[5]); \
    fma4(o4[6], (av), w4_[6]); fma4(o4[7], (av), w4_[7]); }
    OROW(a0.x, 0)  OROW(a0.y, 1)  OROW(a0.z, 2)  OROW(a0.w, 3)
    OROW(a1.x, 4)  OROW(a1.y, 5)  OROW(a1.z, 6)  OROW(a1.w, 7)
    OROW(a2.x, 8)  OROW(a2.y, 9)  OROW(a2.z, 10) OROW(a2.w, 11)
    OROW(a3.x, 12) OROW(a3.y, 13) OROW(a3.z, 14) OROW(a3.w, 15)
    OROW(a4.x, 16) OROW(a4.y, 17) OROW(a4.z, 18) OROW(a4.w, 19)
#undef OROW

    float oo[DIM];
#pragma unroll
    for (int dq = 0; dq < 8; dq++) {
        oo[4 * dq + 0] = o4[dq].x; oo[4 * dq + 1] = o4[dq].y;
        oo[4 * dq + 2] = o4[dq].z; oo[4 * dq + 3] = o4[dq].w;
    }
#pragma unroll
    for (int d = 0; d < DIM; d++) oo[d] += __shfl_xor(oo[d], 4);

    float4* Orow = (float4*)(out + (size_t)side * (NB * NCN * DIM)
                                 + ((size_t)b * NCN + c) * DIM);
    if (half == 0) {
        Orow[0] = make_float4(oo[0], oo[1], oo[2], oo[3]);
        Orow[1] = make_float4(oo[4], oo[5], oo[6], oo[7]);
        Orow[2] = make_float4(oo[8], oo[9], oo[10], oo[11]);
        Orow[3] = make_float4(oo[12], oo[13], oo[14], oo[15]);
    } else {
        Orow[4] = make_float4(oo[16], oo[17], oo[18], oo[19]);
        Orow[5] = make_float4(oo[20], oo[21], oo[22], oo[23]);
        Orow[6] = make_float4(oo[24], oo[25], oo[26], oo[27]);
        Orow[7] = make_float4(oo[28], oo[29], oo[30], oo[31]);
    }
}

// ---------------- host ----------------

extern "C" void kernel_launch(void* const* d_in, const int* in_sizes, int n_in,
                              void* d_out, int out_size, void* d_ws, size_t ws_size,
                              hipStream_t stream) {
    const float* h_from   = (const float*)d_in[0];
    const float* h_to_x   = (const float*)d_in[1];
    const float* h_to_z   = (const float*)d_in[2];
    const float* hx_logit = (const float*)d_in[3];
    const float* hz_logit = (const float*)d_in[4];
    const int*   from_x   = (const int*)d_in[5];
    const int*   to_x     = (const int*)d_in[6];
    const int*   from_z   = (const int*)d_in[7];
    const int*   to_z     = (const int*)d_in[8];
    const float* Wm1_x    = (const float*)d_in[9];
    const float* Wm2_x    = (const float*)d_in[10];
    const float* Wm1_z    = (const float*)d_in[11];
    const float* Wm2_z    = (const float*)d_in[12];
    const float* We1_x    = (const float*)d_in[13];
    const float* We2_x    = (const float*)d_in[14];
    const float* We1_z    = (const float*)d_in[15];
    const float* We2_z    = (const float*)d_in[16];

    // Workspace layout (bytes), end = 85,196,812 (<= proven 85,328,128 budget)
    char* ws = (char*)d_ws;
    u16* U2h_x = (u16*)(ws);                       // 65536*8*20*2 = 20,971,520
    u16* U2h_z = (u16*)(ws + 20971520);            // 20,971,520
    u16* T2h_x = (u16*)(ws + 41943040);            // 32768*8*20*2 = 10,485,760
    u16* P2h_x = (u16*)(ws + 52428800);            // 10,485,760
    u16* T2h_z = (u16*)(ws + 62914560);            // 10,485,760
    u16* P2h_z = (u16*)(ws + 73400320);            // 10,485,760
    u16* ef_x  = (u16*)(ws + 83886080);            // 524,288
    u16* ef_z  = (u16*)(ws + 84410368);            // 524,288
    int* start_x = (int*)(ws + 84934656);          // 131,076
    int* start_z = (int*)(ws + 85065736);          // 131,076
    // counts/cursors alias U2h_x head: dead before precompU writes it (stream order)
    int* cnt_x = (int*)(ws + 0);
    int* cnt_z = (int*)(ws + 131072);
    float* out = (float*)d_out;

    hipMemsetAsync(ws, 0, 262144, stream);  // zero cnt_x + cnt_z
    hist_both<<<2048, 256, 0, stream>>>(to_x, to_z, cnt_x, cnt_z);
    scan_both<<<2, 1024, 0, stream>>>(cnt_x, cnt_z, start_x, start_z);
    scatter_both<<<2048, 256, 0, stream>>>(to_x, from_x, to_z, from_z,
                                           cnt_x, cnt_z, ef_x, ef_z);

    precompU_both<<<4096, 256, 0, stream>>>(h_from, Wm1_x, Wm1_z, U2h_x, U2h_z);
    precompTP_both<<<4096, 256, 0, stream>>>(h_to_x, h_to_z, hx_logit, hz_logit,
                                             Wm1_x, Wm1_z, We1_x, We1_z,
                                             T2h_x, T2h_z, P2h_x, P2h_z);

    agg_kernel<<<2048, 256, 0, stream>>>(U2h_x, U2h_z, T2h_x, T2h_z, P2h_x, P2h_z,
                                         start_x, start_z, ef_x, ef_z,
                                         Wm2_x, Wm2_z, We1_x, We1_z, We2_x, We2_z, out);
}

// Round 11
// 244.931 us; speedup vs baseline: 2.3828x; 1.0059x over previous
//
#include <hip/hip_runtime.h>

// Problem constants (from reference)
#define NVN 65536
#define NCN 32768
#define NB 4
#define DIM 32
#define NE 262144
#define HID 40
#define MSGD 20

#define WE2_STRIDE 36  // padded row stride for we2s (breaks h-row bank aliasing)

typedef unsigned short u16;
typedef unsigned int u32;

// bf16 helpers (RNE pack, cheap unpack)
__device__ __forceinline__ u16 f2bf(float f) {
    u32 u = __float_as_uint(f);
    u += 0x7fff + ((u >> 16) & 1);
    return (u16)(u >> 16);
}
__device__ __forceinline__ float bflo(u32 u) { return __uint_as_float(u << 16); }
__device__ __forceinline__ float bfhi(u32 u) { return __uint_as_float(u & 0xffff0000u); }

__device__ __forceinline__ void fma4(float4& acc, float a, const float4 w) {
    acc.x += a * w.x; acc.y += a * w.y; acc.z += a * w.z; acc.w += a * w.w;
}

// ---------------- CSR build (both sides fused) ----------------

__global__ __launch_bounds__(256) void hist_both(const int* __restrict__ to_x,
                                                 const int* __restrict__ to_z,
                                                 int* __restrict__ cnt_x,
                                                 int* __restrict__ cnt_z) {
    int bid = blockIdx.x;
    int e = (bid & 1023) * 256 + threadIdx.x;
    if (bid < 1024) atomicAdd(&cnt_x[to_x[e]], 1);
    else            atomicAdd(&cnt_z[to_z[e]], 1);
}

__global__ __launch_bounds__(1024) void scan_both(int* __restrict__ cnt_x,
                                                  int* __restrict__ cnt_z,
                                                  int* __restrict__ start_x,
                                                  int* __restrict__ start_z) {
    int side = blockIdx.x;
    int* counts = side ? cnt_z : cnt_x;   // re-written in place as scatter cursor
    int* start  = side ? start_z : start_x;
    __shared__ int sd[1024];
    int t = threadIdx.x;
    int base = t * 32;
    int local[32];
    int s = 0;
#pragma unroll
    for (int i = 0; i < 32; i++) { local[i] = counts[base + i]; s += local[i]; }
    sd[t] = s;
    __syncthreads();
    for (int off = 1; off < 1024; off <<= 1) {
        int v = (t >= off) ? sd[t - off] : 0;
        __syncthreads();
        sd[t] += v;
        __syncthreads();
    }
    int run = sd[t] - s;
#pragma unroll
    for (int i = 0; i < 32; i++) {
        start[base + i] = run;
        counts[base + i] = run;   // cursor init
        run += local[i];
    }
    if (t == 1023) start[NCN] = run;
}

__global__ __launch_bounds__(256) void scatter_both(const int* __restrict__ to_x,
                                                    const int* __restrict__ from_x,
                                                    const int* __restrict__ to_z,
                                                    const int* __restrict__ from_z,
                                                    int* __restrict__ cnt_x,
                                                    int* __restrict__ cnt_z,
                                                    u16* __restrict__ ef_x,
                                                    u16* __restrict__ ef_z) {
    int bid = blockIdx.x;
    int e = (bid & 1023) * 256 + threadIdx.x;
    const int* t; const int* f; int* cur; u16* ef;
    if (bid < 1024) { t = to_x; f = from_x; cur = cnt_x; ef = ef_x; }
    else            { t = to_z; f = from_z; cur = cnt_z; ef = ef_z; }
    int c = t[e];
    int pos = atomicAdd(&cur[c], 1);
    ef[pos] = (u16)f[e];
}

// ------- Precompute U2h, BOTH sides, 20 outputs/thread, LANE-INTERLEAVED layout -------
// Per v: 320B line; lane l8's 20 bf16 live at {v*320 + l8*16 (16B), +128+l8*16 (16B),
// +256+l8*8 (8B)} so agg's gather instructions are contiguous per 8-lane group
// (r10 layout was stride-40B per lane -> ~5x transaction amplification in the TA).

__global__ __launch_bounds__(256) void precompU_both(const float* __restrict__ h_from,
                                                     const float* __restrict__ Wm1_x,
                                                     const float* __restrict__ Wm1_z,
                                                     u16* __restrict__ U2h_x,
                                                     u16* __restrict__ U2h_z) {
    int side = blockIdx.x >> 11;
    const float* Wm1 = side ? Wm1_z : Wm1_x;
    u16* U2h = side ? U2h_z : U2h_x;

    __shared__ __attribute__((aligned(16))) float w[DIM * HID];
    int tid = threadIdx.x;
    for (int i = tid; i < DIM * HID; i += 256) w[i] = Wm1[i];
    __syncthreads();

    int gt = (blockIdx.x & 2047) * 256 + tid;
    int v = gt >> 3;
    int l8 = gt & 7;
    int b = l8 & 3;
    int hoff = (l8 >> 2) * 20;

    const float4* hf4 = (const float4*)(h_from + ((size_t)b * NVN + v) * DIM);
    float4 acc4[5];
#pragma unroll
    for (int jq = 0; jq < 5; jq++) acc4[jq] = make_float4(0.f, 0.f, 0.f, 0.f);
#pragma unroll
    for (int q = 0; q < DIM / 4; q++) {
        float4 x = hf4[q];
#define WROW(xr, row) { const float4* w4_ = (const float4*)(w + (row) * HID + hoff); \
        fma4(acc4[0], (xr), w4_[0]); fma4(acc4[1], (xr), w4_[1]); \
        fma4(acc4[2], (xr), w4_[2]); fma4(acc4[3], (xr), w4_[3]); \
        fma4(acc4[4], (xr), w4_[4]); }
        WROW(x.x, 4 * q + 0) WROW(x.y, 4 * q + 1) WROW(x.z, 4 * q + 2) WROW(x.w, 4 * q + 3)
#undef WROW
    }
    u32 p[10];
#pragma unroll
    for (int jq = 0; jq < 5; jq++) {
        p[2 * jq]     = (u32)f2bf(acc4[jq].x) | ((u32)f2bf(acc4[jq].y) << 16);
        p[2 * jq + 1] = (u32)f2bf(acc4[jq].z) | ((u32)f2bf(acc4[jq].w) << 16);
    }
    char* dst = (char*)U2h + (size_t)v * 320;
    *(uint4*)(dst + l8 * 16)       = make_uint4(p[0], p[1], p[2], p[3]);
    *(uint4*)(dst + 128 + l8 * 16) = make_uint4(p[4], p[5], p[6], p[7]);
    *(uint2*)(dst + 256 + l8 * 8)  = make_uint2(p[8], p[9]);
}

// ------- Precompute T2h/P2h bf16, BOTH sides, 20 out/thread, same interleaved layout -------

__global__ __launch_bounds__(256) void precompTP_both(
        const float* __restrict__ h_to_x, const float* __restrict__ h_to_z,
        const float* __restrict__ logit_x, const float* __restrict__ logit_z,
        const float* __restrict__ Wm1_x, const float* __restrict__ Wm1_z,
        const float* __restrict__ We1_x, const float* __restrict__ We1_z,
        u16* __restrict__ T2h_x, u16* __restrict__ T2h_z,
        u16* __restrict__ P2h_x, u16* __restrict__ P2h_z) {
    int side = blockIdx.x >> 11;
    const float* h_to = side ? h_to_z : h_to_x;
    const float* logit = side ? logit_z : logit_x;
    const float* Wm1 = side ? Wm1_z : Wm1_x;
    const float* We1 = side ? We1_z : We1_x;
    u16* T2h = side ? T2h_z : T2h_x;
    u16* P2h = side ? P2h_z : P2h_x;

    __shared__ __attribute__((aligned(16))) float wm1b[DIM * HID];
    __shared__ __attribute__((aligned(16))) float we1b[DIM * HID];
    __shared__ float we1l[HID];
    int tid = threadIdx.x;
    for (int i = tid; i < DIM * HID; i += 256) {
        wm1b[i] = Wm1[DIM * HID + i];   // rows 32..63 of Wm1
        we1b[i] = We1[MSGD * HID + i];  // rows 20..51 of We1
    }
    if (tid < HID) we1l[tid] = We1[(MSGD + DIM) * HID + tid];  // row 52
    __syncthreads();

    int gt = (blockIdx.x & 2047) * 256 + tid;
    int c = gt >> 4;
    int l16 = gt & 15;
    int b = l16 & 3;
    int half = (l16 >> 2) & 1;
    int which = l16 >> 3;          // 0: T, 1: P
    int hoff = half * 20;

    const float4* h4 = (const float4*)(h_to + ((size_t)b * NCN + c) * DIM);
    float lg = logit[(size_t)b * NCN + c];
    float lginit = which ? lg : 0.f;
    const float* wsel = which ? we1b : wm1b;

    float4 acc4[5];
    {
        const float4* wl = (const float4*)(we1l + hoff);
#pragma unroll
        for (int jq = 0; jq < 5; jq++) {
            float4 wv = wl[jq];
            acc4[jq] = make_float4(lginit * wv.x, lginit * wv.y, lginit * wv.z, lginit * wv.w);
        }
    }
#pragma unroll
    for (int q = 0; q < DIM / 4; q++) {
        float4 x = h4[q];
#define WROW(xr, row) { const float4* w4_ = (const float4*)(wsel + (row) * HID + hoff); \
        fma4(acc4[0], (xr), w4_[0]); fma4(acc4[1], (xr), w4_[1]); \
        fma4(acc4[2], (xr), w4_[2]); fma4(acc4[3], (xr), w4_[3]); \
        fma4(acc4[4], (xr), w4_[4]); }
        WROW(x.x, 4 * q + 0) WROW(x.y, 4 * q + 1) WROW(x.z, 4 * q + 2) WROW(x.w, 4 * q + 3)
#undef WROW
    }
    u32 p[10];
#pragma unroll
    for (int jq = 0; jq < 5; jq++) {
        p[2 * jq]     = (u32)f2bf(acc4[jq].x) | ((u32)f2bf(acc4[jq].y) << 16);
        p[2 * jq + 1] = (u32)f2bf(acc4[jq].z) | ((u32)f2bf(acc4[jq].w) << 16);
    }
    int l8d = half * 4 + b;
    char* dst = (char*)(which ? P2h : T2h) + (size_t)c * 320;
    *(uint4*)(dst + l8d * 16)       = make_uint4(p[0], p[1], p[2], p[3]);
    *(uint4*)(dst + 128 + l8d * 16) = make_uint4(p[4], p[5], p[6], p[7]);
    *(uint2*)(dst + 256 + l8d * 8)  = make_uint2(p[8], p[9]);
}

// ------- Fused aggregate + embed MLP, BOTH SIDES in one dispatch -------
// 8 lanes per (c): lane = (b, half) owns 20 comps. Interleaved staging layout makes
// each gather instruction contiguous per group (uint4/uint4/uint2 = 3 loads/edge).
// NOTE: no min-waves clamp — VGPR must float (~76) or the edge loop spills
// (r9 fusion attempt: VGPR 256, 577MB scratch writes, 571us — reverted).

__global__ __launch_bounds__(256) void agg_kernel(
        const u16* __restrict__ U2h_x, const u16* __restrict__ U2h_z,
        const u16* __restrict__ T2h_x, const u16* __restrict__ T2h_z,
        const u16* __restrict__ P2h_x, const u16* __restrict__ P2h_z,
        const int* __restrict__ start_x, const int* __restrict__ start_z,
        const u16* __restrict__ ef_x, const u16* __restrict__ ef_z,
        const float* __restrict__ Wm2_x, const float* __restrict__ Wm2_z,
        const float* __restrict__ We1_x, const float* __restrict__ We1_z,
        const float* __restrict__ We2_x, const float* __restrict__ We2_z,
        float* __restrict__ out) {
    int side = blockIdx.x >> 10;
    const u16* U2h = side ? U2h_z : U2h_x;
    const u16* T2h = side ? T2h_z : T2h_x;
    const u16* P2h = side ? P2h_z : P2h_x;
    const int* start = side ? start_z : start_x;
    const u16* ef = side ? ef_z : ef_x;
    const float* Wm2 = side ? Wm2_z : Wm2_x;
    const float* We1 = side ? We1_z : We1_x;
    const float* We2 = side ? We2_z : We2_x;

    __shared__ __attribute__((aligned(16))) float wm2s[HID * MSGD];        // [40][20]
    __shared__ __attribute__((aligned(16))) float we1s[MSGD * HID];        // [20][40]
    __shared__ __attribute__((aligned(16))) float we2s[HID * WE2_STRIDE];  // [40][36]
    int tid = threadIdx.x;
    for (int i = tid; i < HID * MSGD; i += 256) { wm2s[i] = Wm2[i]; we1s[i] = We1[i]; }
    for (int i = tid; i < HID * DIM; i += 256) {
        int h = i >> 5, d = i & 31;
        we2s[h * WE2_STRIDE + d] = We2[i];
    }
    __syncthreads();

    int gt = (blockIdx.x & 1023) * 256 + tid;
    int c = gt >> 3;
    int l8 = gt & 7;
    int b = l8 & 3;
    int half = l8 >> 2;
    int hoff = half * 20;

    int off16a = l8 * 16;
    int off16b = 128 + l8 * 16;
    int off8c = 256 + l8 * 8;

    // T slice: 20 bf16 -> 20 f32 regs (interleaved layout)
    float t[20];
    {
        const char* tv = (const char*)T2h + (size_t)c * 320;
        uint4 T0 = *(const uint4*)(tv + off16a);
        uint4 T1 = *(const uint4*)(tv + off16b);
        uint2 Tc = *(const uint2*)(tv + off8c);
        t[0] = bflo(T0.x);  t[1] = bfhi(T0.x);  t[2] = bflo(T0.y);  t[3] = bfhi(T0.y);
        t[4] = bflo(T0.z);  t[5] = bfhi(T0.z);  t[6] = bflo(T0.w);  t[7] = bfhi(T0.w);
        t[8] = bflo(T1.x);  t[9] = bfhi(T1.x);  t[10] = bflo(T1.y); t[11] = bfhi(T1.y);
        t[12] = bflo(T1.z); t[13] = bfhi(T1.z); t[14] = bflo(T1.w); t[15] = bfhi(T1.w);
        t[16] = bflo(Tc.x); t[17] = bfhi(Tc.x); t[18] = bflo(Tc.y); t[19] = bfhi(Tc.y);
    }

    float s[20];
#pragma unroll
    for (int k = 0; k < 20; k++) s[k] = 0.f;

    int e0 = start[c], e1 = start[c + 1];
    const char* Ubase = (const char*)U2h;
    int i = e0;
    int cnt = e1 - e0;
    int vA = (cnt > 0) ? (int)ef[i] : 0;
    int vB = (cnt > 1) ? (int)ef[i + 1] : 0;

#define CONS4(W, base) { \
    s[(base) + 0] += fmaxf(bflo(W.x) + t[(base) + 0], 0.f); \
    s[(base) + 1] += fmaxf(bfhi(W.x) + t[(base) + 1], 0.f); \
    s[(base) + 2] += fmaxf(bflo(W.y) + t[(base) + 2], 0.f); \
    s[(base) + 3] += fmaxf(bfhi(W.y) + t[(base) + 3], 0.f); \
    s[(base) + 4] += fmaxf(bflo(W.z) + t[(base) + 4], 0.f); \
    s[(base) + 5] += fmaxf(bfhi(W.z) + t[(base) + 5], 0.f); \
    s[(base) + 6] += fmaxf(bflo(W.w) + t[(base) + 6], 0.f); \
    s[(base) + 7] += fmaxf(bfhi(W.w) + t[(base) + 7], 0.f); }
#define CONS2(W, base) { \
    s[(base) + 0] += fmaxf(bflo(W.x) + t[(base) + 0], 0.f); \
    s[(base) + 1] += fmaxf(bfhi(W.x) + t[(base) + 1], 0.f); \
    s[(base) + 2] += fmaxf(bflo(W.y) + t[(base) + 2], 0.f); \
    s[(base) + 3] += fmaxf(bfhi(W.y) + t[(base) + 3], 0.f); }

    while (cnt >= 2) {
        const char* pa = Ubase + (size_t)vA * 320;
        const char* pb = Ubase + (size_t)vB * 320;
        uint4 A0 = *(const uint4*)(pa + off16a);
        uint4 A1 = *(const uint4*)(pa + off16b);
        uint2 A2 = *(const uint2*)(pa + off8c);
        uint4 B0 = *(const uint4*)(pb + off16a);
        uint4 B1 = *(const uint4*)(pb + off16b);
        uint2 B2 = *(const uint2*)(pb + off8c);
        int vA2 = (cnt > 2) ? (int)ef[i + 2] : 0;
        int vB2 = (cnt > 3) ? (int)ef[i + 3] : 0;
        CONS4(A0, 0) CONS4(A1, 8) CONS2(A2, 16)
        CONS4(B0, 0) CONS4(B1, 8) CONS2(B2, 16)
        vA = vA2; vB = vB2; i += 2; cnt -= 2;
    }
    if (cnt == 1) {
        const char* pa = Ubase + (size_t)vA * 320;
        uint4 A0 = *(const uint4*)(pa + off16a);
        uint4 A1 = *(const uint4*)(pa + off16b);
        uint2 A2 = *(const uint2*)(pa + off8c);
        CONS4(A0, 0) CONS4(A1, 8) CONS2(A2, 16)
    }
#undef CONS4
#undef CONS2

    // ---- m partial: this lane's 20 h-rows of Wm2 ----
    float4 m4[5];
#pragma unroll
    for (int kq = 0; kq < 5; kq++) m4[kq] = make_float4(0.f, 0.f, 0.f, 0.f);
    const float* wmbase = wm2s + hoff * MSGD;
#define MROW(sv, k) { const float4* w4_ = (const float4*)(wmbase + (k) * MSGD); \
    fma4(m4[0], (sv), w4_[0]); fma4(m4[1], (sv), w4_[1]); fma4(m4[2], (sv), w4_[2]); \
    fma4(m4[3], (sv), w4_[3]); fma4(m4[4], (sv), w4_[4]); }
    MROW(s[0], 0)   MROW(s[1], 1)   MROW(s[2], 2)   MROW(s[3], 3)
    MROW(s[4], 4)   MROW(s[5], 5)   MROW(s[6], 6)   MROW(s[7], 7)
    MROW(s[8], 8)   MROW(s[9], 9)   MROW(s[10], 10) MROW(s[11], 11)
    MROW(s[12], 12) MROW(s[13], 13) MROW(s[14], 14) MROW(s[15], 15)
    MROW(s[16], 16) MROW(s[17], 17) MROW(s[18], 18) MROW(s[19], 19)
#undef MROW

    float mm[MSGD];
#pragma unroll
    for (int kq = 0; kq < 5; kq++) {
        mm[4 * kq + 0] = m4[kq].x; mm[4 * kq + 1] = m4[kq].y;
        mm[4 * kq + 2] = m4[kq].z; mm[4 * kq + 3] = m4[kq].w;
    }
    // combine the two comp-halves (lane ^ 4) -> full m in every lane
#pragma unroll
    for (int k = 0; k < MSGD; k++) mm[k] += __shfl_xor(mm[k], 4);

    // ---- a = relu(m @ We1[0:20] + P) for this lane's 20 components ----
    float4 a0, a1, a2, a3, a4;
    {
        const char* pv = (const char*)P2h + (size_t)c * 320;
        uint4 P0 = *(const uint4*)(pv + off16a);
        uint4 P1 = *(const uint4*)(pv + off16b);
        uint2 Pc = *(const uint2*)(pv + off8c);
        a0 = make_float4(bflo(P0.x), bfhi(P0.x), bflo(P0.y), bfhi(P0.y));
        a1 = make_float4(bflo(P0.z), bfhi(P0.z), bflo(P0.w), bfhi(P0.w));
        a2 = make_float4(bflo(P1.x), bfhi(P1.x), bflo(P1.y), bfhi(P1.y));
        a3 = make_float4(bflo(P1.z), bfhi(P1.z), bflo(P1.w), bfhi(P1.w));
        a4 = make_float4(bflo(Pc.x), bfhi(Pc.x), bflo(Pc.y), bfhi(Pc.y));
    }
#pragma unroll
    for (int k = 0; k < MSGD; k++) {
        float mk = mm[k];
        const float4* w4 = (const float4*)(we1s + k * HID + hoff);
        fma4(a0, mk, w4[0]); fma4(a1, mk, w4[1]); fma4(a2, mk, w4[2]);
        fma4(a3, mk, w4[3]); fma4(a4, mk, w4[4]);
    }
    a0.x = fmaxf(a0.x, 0.f); a0.y = fmaxf(a0.y, 0.f); a0.z = fmaxf(a0.z, 0.f); a0.w = fmaxf(a0.w, 0.f);
    a1.x = fmaxf(a1.x, 0.f); a1.y = fmaxf(a1.y, 0.f); a1.z = fmaxf(a1.z, 0.f); a1.w = fmaxf(a1.w, 0.f);
    a2.x = fmaxf(a2.x, 0.f); a2.y = fmaxf(a2.y, 0.f); a2.z = fmaxf(a2.z, 0.f); a2.w = fmaxf(a2.w, 0.f);
    a3.x = fmaxf(a3.x, 0.f); a3.y = fmaxf(a3.y, 0.f); a3.z = fmaxf(a3.z, 0.f); a3.w = fmaxf(a3.w, 0.f);
    a4.x = fmaxf(a4.x, 0.f); a4.y = fmaxf(a4.y, 0.f); a4.z = fmaxf(a4.z, 0.f); a4.w = fmaxf(a4.w, 0.f);

    // ---- o partial: this lane's 20 h-rows of We2 ----
    float4 o4[8];
#pragma unroll
    for (int dq = 0; dq < 8; dq++) o4[dq] = make_float4(0.f, 0.f, 0.f, 0.f);
    const float* wobase = we2s + hoff * WE2_STRIDE;
#define OROW(av, k) { const float4* w4_ = (const float4*)(wobase + (k) * WE2_STRIDE); \
    fma4(o4[0], (av), w4_[0]); fma4(o4[1], (av), w4_[1]); fma4(o4[2], (av), w4_[2]); \
    fma4(o4[3], (av), w4_[3]); fma4(o4[4], (av), w4_[4]); fma4(o4[5], (av), w4_[5]); \
    fma4(o4[6], (av), w4_[6]); fma4(o4[7], (av), w4_[7]); }
    OROW(a0.x, 0)  OROW(a0.y, 1)  OROW(a0.z, 2)  OROW(a0.w, 3)
    OROW(a1.x, 4)  OROW(a1.y, 5)  OROW(a1.z, 6)  OROW(a1.w, 7)
    OROW(a2.x, 8)  OROW(a2.y, 9)  OROW(a2.z, 10) OROW(a2.w, 11)
    OROW(a3.x, 12) OROW(a3.y, 13) OROW(a3.z, 14) OROW(a3.w, 15)
    OROW(a4.x, 16) OROW(a4.y, 17) OROW(a4.z, 18) OROW(a4.w, 19)
#undef OROW

    float oo[DIM];
#pragma unroll
    for (int dq = 0; dq < 8; dq++) {
        oo[4 * dq + 0] = o4[dq].x; oo[4 * dq + 1] = o4[dq].y;
        oo[4 * dq + 2] = o4[dq].z; oo[4 * dq + 3] = o4[dq].w;
    }
#pragma unroll
    for (int d = 0; d < DIM; d++) oo[d] += __shfl_xor(oo[d], 4);

    float4* Orow = (float4*)(out + (size_t)side * (NB * NCN * DIM)
                                 + ((size_t)b * NCN + c) * DIM);
    if (half == 0) {
        Orow[0] = make_float4(oo[0], oo[1], oo[2], oo[3]);
        Orow[1] = make_float4(oo[4], oo[5], oo[6], oo[7]);
        Orow[2] = make_float4(oo[8], oo[9], oo[10], oo[11]);
        Orow[3] = make_float4(oo[12], oo[13], oo[14], oo[15]);
    } else {
        Orow[4] = make_float4(oo[16], oo[17], oo[18], oo[19]);
        Orow[5] = make_float4(oo[20], oo[21], oo[22], oo[23]);
        Orow[6] = make_float4(oo[24], oo[25], oo[26], oo[27]);
        Orow[7] = make_float4(oo[28], oo[29], oo[30], oo[31]);
    }
}

// ---------------- host ----------------

extern "C" void kernel_launch(void* const* d_in, const int* in_sizes, int n_in,
                              void* d_out, int out_size, void* d_ws, size_t ws_size,
                              hipStream_t stream) {
    const float* h_from   = (const float*)d_in[0];
    const float* h_to_x   = (const float*)d_in[1];
    const float* h_to_z   = (const float*)d_in[2];
    const float* hx_logit = (const float*)d_in[3];
    const float* hz_logit = (const float*)d_in[4];
    const int*   from_x   = (const int*)d_in[5];
    const int*   to_x     = (const int*)d_in[6];
    const int*   from_z   = (const int*)d_in[7];
    const int*   to_z     = (const int*)d_in[8];
    const float* Wm1_x    = (const float*)d_in[9];
    const float* Wm2_x    = (const float*)d_in[10];
    const float* Wm1_z    = (const float*)d_in[11];
    const float* Wm2_z    = (const float*)d_in[12];
    const float* We1_x    = (const float*)d_in[13];
    const float* We2_x    = (const float*)d_in[14];
    const float* We1_z    = (const float*)d_in[15];
    const float* We2_z    = (const float*)d_in[16];

    // Workspace layout (bytes), end = 85,196,812 (<= proven 85,328,128 budget)
    char* ws = (char*)d_ws;
    u16* U2h_x = (u16*)(ws);                       // 65536*8*20*2 = 20,971,520
    u16* U2h_z = (u16*)(ws + 20971520);            // 20,971,520
    u16* T2h_x = (u16*)(ws + 41943040);            // 32768*8*20*2 = 10,485,760
    u16* P2h_x = (u16*)(ws + 52428800);            // 10,485,760
    u16* T2h_z = (u16*)(ws + 62914560);            // 10,485,760
    u16* P2h_z = (u16*)(ws + 73400320);            // 10,485,760
    u16* ef_x  = (u16*)(ws + 83886080);            // 524,288
    u16* ef_z  = (u16*)(ws + 84410368);            // 524,288
    int* start_x = (int*)(ws + 84934656);          // 131,076
    int* start_z = (int*)(ws + 85065736);          // 131,076
    // counts/cursors alias U2h_x head: dead before precompU writes it (stream order)
    int* cnt_x = (int*)(ws + 0);
    int* cnt_z = (int*)(ws + 131072);
    float* out = (float*)d_out;

    hipMemsetAsync(ws, 0, 262144, stream);  // zero cnt_x + cnt_z
    hist_both<<<2048, 256, 0, stream>>>(to_x, to_z, cnt_x, cnt_z);
    scan_both<<<2, 1024, 0, stream>>>(cnt_x, cnt_z, start_x, start_z);
    scatter_both<<<2048, 256, 0, stream>>>(to_x, from_x, to_z, from_z,
                                           cnt_x, cnt_z, ef_x, ef_z);

    precompU_both<<<4096, 256, 0, stream>>>(h_from, Wm1_x, Wm1_z, U2h_x, U2h_z);
    precompTP_both<<<4096, 256, 0, stream>>>(h_to_x, h_to_z, hx_logit, hz_logit,
                                             Wm1_x, Wm1_z, We1_x, We1_z,
                                             T2h_x, T2h_z, P2h_x, P2h_z);

    agg_kernel<<<2048, 256, 0, stream>>>(U2h_x, U2h_z, T2h_x, T2h_z, P2h_x, P2h_z,
                                         start_x, start_z, ef_x, ef_z,
                                         Wm2_x, Wm2_z, We1_x, We1_z, We2_x, We2_z, out);
}